// Round 10
// baseline (100.241 us; speedup 1.0000x reference)
//
#include <hip/hip_runtime.h>
#include <math.h>

constexpr int Bn = 1024, Vn = 5023;
constexpr int NB = 16;            // batches per block (2 halves x 8)
constexpr int PARAM_STRIDE = 96;  // 36 pose_feat + 5*12 A per batch (floats)

typedef int i32x16 __attribute__((ext_vector_type(16)));
typedef int i32x8 __attribute__((ext_vector_type(8)));
typedef int i32x4 __attribute__((ext_vector_type(4)));
typedef __fp16 half2_t __attribute__((ext_vector_type(2)));

// ---------------------------------------------------------------------------
// Kernel A: per-batch pose math. 1 thread per batch.
// params layout per batch: [0..35] pose_feat (joint-1..4, row-major 3x3 - I),
//                          [36..95] A_j as 3x4 row-major, j=0..4
// ---------------------------------------------------------------------------

__device__ inline void rodrigues3(float rx, float ry, float rz, float R[9]) {
    const float eps = 1e-8f;
    float ax = rx + eps, ay = ry + eps, az = rz + eps;
    float ang = sqrtf(ax * ax + ay * ay + az * az);
    float inv = 1.0f / ang;
    float dx = rx * inv, dy = ry * inv, dz = rz * inv;
    float s = sinf(ang), c = cosf(ang), omc = 1.0f - c;
    float K[9] = {0.f, -dz, dy, dz, 0.f, -dx, -dy, dx, 0.f};
    float K2[9];
#pragma unroll
    for (int r = 0; r < 3; r++)
#pragma unroll
        for (int k = 0; k < 3; k++) {
            float acc = 0.f;
#pragma unroll
            for (int i = 0; i < 3; i++) acc += K[r * 3 + i] * K[i * 3 + k];
            K2[r * 3 + k] = acc;
        }
#pragma unroll
    for (int i = 0; i < 9; i++) R[i] = s * K[i] + omc * K2[i];
    R[0] += 1.f; R[4] += 1.f; R[8] += 1.f;
}

__device__ inline void rot6d(const float* x, float R[9]) {
    float a1x = x[0], a1y = x[1], a1z = x[2];
    float a2x = x[3], a2y = x[4], a2z = x[5];
    float n1 = sqrtf(a1x * a1x + a1y * a1y + a1z * a1z);
    float b1x = a1x / n1, b1y = a1y / n1, b1z = a1z / n1;
    float d = b1x * a2x + b1y * a2y + b1z * a2z;
    float tx = a2x - d * b1x, ty = a2y - d * b1y, tz = a2z - d * b1z;
    float n2 = sqrtf(tx * tx + ty * ty + tz * tz);
    float b2x = tx / n2, b2y = ty / n2, b2z = tz / n2;
    float b3x = b1y * b2z - b1z * b2y;
    float b3y = b1z * b2x - b1x * b2z;
    float b3z = b1x * b2y - b1y * b2x;
    R[0] = b1x; R[1] = b1y; R[2] = b1z;
    R[3] = b2x; R[4] = b2y; R[5] = b2z;
    R[6] = b3x; R[7] = b3y; R[8] = b3z;
}

__device__ inline void compose(const float* Rp, const float* tp,
                               const float* Ri, const float* ti,
                               float* Ro, float* to) {
#pragma unroll
    for (int r = 0; r < 3; r++) {
#pragma unroll
        for (int c = 0; c < 3; c++) {
            Ro[r * 3 + c] = Rp[r * 3 + 0] * Ri[0 * 3 + c] +
                            Rp[r * 3 + 1] * Ri[1 * 3 + c] +
                            Rp[r * 3 + 2] * Ri[2 * 3 + c];
        }
        to[r] = Rp[r * 3 + 0] * ti[0] + Rp[r * 3 + 1] * ti[1] +
                Rp[r * 3 + 2] * ti[2] + tp[r];
    }
}

__global__ void flame_params_kernel(const float* __restrict__ g6,
                                    const float* __restrict__ neck,
                                    const float* __restrict__ jaw,
                                    const float* __restrict__ eye,
                                    const float* __restrict__ jrest,
                                    float* __restrict__ params) {
    int b = blockIdx.x * blockDim.x + threadIdx.x;
    if (b >= Bn) return;

    float R[5][9];
    rot6d(g6 + b * 6, R[0]);
    rodrigues3(neck[b * 3 + 0], neck[b * 3 + 1], neck[b * 3 + 2], R[1]);
    rodrigues3(jaw[b * 3 + 0], jaw[b * 3 + 1], jaw[b * 3 + 2], R[2]);
    rodrigues3(eye[b * 6 + 0], eye[b * 6 + 1], eye[b * 6 + 2], R[3]);
    rodrigues3(eye[b * 6 + 3], eye[b * 6 + 4], eye[b * 6 + 5], R[4]);

    float j[5][3];
#pragma unroll
    for (int i = 0; i < 5; i++) {
        j[i][0] = jrest[b * 15 + i * 3 + 0];
        j[i][1] = jrest[b * 15 + i * 3 + 1];
        j[i][2] = jrest[b * 15 + i * 3 + 2];
    }
    float rel[5][3];
#pragma unroll
    for (int c = 0; c < 3; c++) {
        rel[0][c] = j[0][c];
        rel[1][c] = j[1][c] - j[0][c];
        rel[2][c] = j[2][c] - j[1][c];
        rel[3][c] = j[3][c] - j[1][c];
        rel[4][c] = j[4][c] - j[1][c];
    }

    float CR[5][9], CT[5][3];
#pragma unroll
    for (int i = 0; i < 9; i++) CR[0][i] = R[0][i];
#pragma unroll
    for (int c = 0; c < 3; c++) CT[0][c] = rel[0][c];
    compose(CR[0], CT[0], R[1], rel[1], CR[1], CT[1]);
    compose(CR[1], CT[1], R[2], rel[2], CR[2], CT[2]);
    compose(CR[1], CT[1], R[3], rel[3], CR[3], CT[3]);
    compose(CR[1], CT[1], R[4], rel[4], CR[4], CT[4]);

    float* P = params + b * PARAM_STRIDE;
#pragma unroll
    for (int jj = 0; jj < 4; jj++)
#pragma unroll
        for (int r = 0; r < 3; r++)
#pragma unroll
            for (int c = 0; c < 3; c++)
                P[jj * 9 + r * 3 + c] = R[jj + 1][r * 3 + c] - (r == c ? 1.f : 0.f);
#pragma unroll
    for (int i = 0; i < 5; i++) {
#pragma unroll
        for (int r = 0; r < 3; r++) {
            float t = CT[i][r] - (CR[i][r * 3 + 0] * j[i][0] +
                                  CR[i][r * 3 + 1] * j[i][1] +
                                  CR[i][r * 3 + 2] * j[i][2]);
            P[36 + i * 12 + r * 4 + 0] = CR[i][r * 3 + 0];
            P[36 + i * 12 + r * 4 + 1] = CR[i][r * 3 + 1];
            P[36 + i * 12 + r * 4 + 2] = CR[i][r * 3 + 2];
            P[36 + i * 12 + r * 4 + 3] = t;
        }
    }
}

// ---------------------------------------------------------------------------
// Kernel B. 9-round diagnosis: ~96 broadcast param dwords per batch always
// went through the per-lane vector memory path (compiler never scalarizes).
// Fix: explicit inline-asm s_load -> params live in SGPRs, consumed as the
// 1-SGPR operand of v_fma. pd: fp16-packed LDS, linear 54-dword rows
// (conflict-free b64 pattern), 128-vertex tile = 27.6 KB -> 4 blocks/CU.
// 256 thr = 128 vertices x 2 batch-halves; C row re-read per 4 batches.
// ---------------------------------------------------------------------------

#define FCV(k)                                                        \
    __int_as_float((k) < 16 ? fc0[(k)]                                \
                   : (k) < 32 ? fc1[(k) - 16] : fc2[(k) - 32])
#define AFV(k)                                                        \
    __int_as_float((k) < 16 ? A0[(k)]                                 \
                   : (k) < 32 ? A1[(k) - 16]                          \
                   : (k) < 48 ? A2[(k) - 32]                          \
                   : (k) < 56 ? A3[(k) - 48] : A4[(k) - 56])
#define ACCSEL(c) ((c) == 0 ? px : (c) == 1 ? py : pz)

__global__ __launch_bounds__(256, 4) void flame_main_kernel(
    const float* __restrict__ vsh, const float* __restrict__ lbs,
    const float* __restrict__ pdirs, const float* __restrict__ params,
    float* __restrict__ out) {
    const int tid = threadIdx.x;
    const int vt = tid & 127;  // vertex within tile
    const int bh = __builtin_amdgcn_readfirstlane(tid >> 7);  // wave-uniform
    const int v = blockIdx.x * 128 + vt;
    const bool valid = v < Vn;
    const int vc = valid ? v : (Vn - 1);
    const int b0 = blockIdx.y * NB + bh * (NB / 2);

    __shared__ uint32_t shd[128 * 54];  // 27,648 B

    // ---- stage 128 pd rows, f32 -> fp16(RNE)-packed, linear layout ----
    {
        const size_t g0 = (size_t)blockIdx.x * 128 * 108;
        const size_t gmax = (size_t)Vn * 108 - 2;
#pragma unroll
        for (int i = 0; i < 27; i++) {
            int p = i * 256 + tid;  // packed-dword index in tile [0,6912)
            size_t g = g0 + (size_t)p * 2;
            if (g > gmax) g = gmax;
            float2 f = *reinterpret_cast<const float2*>(pdirs + g);
            half2_t h;
            h.x = (__fp16)f.x;
            h.y = (__fp16)f.y;
            shd[p] = __builtin_bit_cast(uint32_t, h);
        }
    }
    __syncthreads();

    float wgt[5];
#pragma unroll
    for (int jj = 0; jj < 5; jj++) wgt[jj] = lbs[(size_t)vc * 5 + jj];

    const uint2* __restrict__ my =
        reinterpret_cast<const uint2*>(shd + vt * 54);  // 8B-aligned

#pragma unroll 1
    for (int g2 = 0; g2 < 2; g2++) {
        // one conflict-free LDS row read shared by 4 batches
        uint2 C[27];
#pragma unroll
        for (int i = 0; i < 27; i++) C[i] = my[i];

#pragma unroll
        for (int u = 0; u < 4; u++) {
            const int b = b0 + g2 * 4 + u;
            const float* P = params + (size_t)b * PARAM_STRIDE;
            const size_t base = ((size_t)b * Vn + vc) * 3;

            // per-lane VMEM in the loop: only vsh (+ the store)
            float a0 = vsh[base + 0];
            float a1 = vsh[base + 1];
            float a2 = vsh[base + 2];

            // ---- fc[36] via scalar pipe ----
            i32x16 fc0, fc1;
            i32x4 fc2;
            asm volatile("s_load_dwordx16 %0, %1, 0x0" : "=s"(fc0) : "s"(P));
            asm volatile("s_load_dwordx16 %0, %1, 0x40" : "=s"(fc1) : "s"(P));
            asm volatile("s_load_dwordx4 %0, %1, 0x80" : "=s"(fc2) : "s"(P));
            asm volatile("s_waitcnt lgkmcnt(0)" ::: "memory");
            __builtin_amdgcn_sched_barrier(0);

            float px = 0.f, py = 0.f, pz = 0.f;
#pragma unroll
            for (int i = 0; i < 54; i++) {
                uint32_t dw = (i & 1) ? C[i >> 1].y : C[i >> 1].x;
                half2_t h = __builtin_bit_cast(half2_t, dw);
                float plo = (float)h.x;
                float phi = (float)h.y;
                const int e0 = 2 * i, e1 = 2 * i + 1;
                ACCSEL(e0 % 3) = fmaf(FCV(e0 / 3), plo, ACCSEL(e0 % 3));
                ACCSEL(e1 % 3) = fmaf(FCV(e1 / 3), phi, ACCSEL(e1 % 3));
            }
            float x = a0 + px, y = a1 + py, z = a2 + pz;

            // ---- A[60] via scalar pipe (fc regs dead -> SGPRs reused) ----
            i32x16 A0, A1, A2;
            i32x8 A3;
            i32x4 A4;
            asm volatile("s_load_dwordx16 %0, %1, 0x90" : "=s"(A0) : "s"(P));
            asm volatile("s_load_dwordx16 %0, %1, 0xD0" : "=s"(A1) : "s"(P));
            asm volatile("s_load_dwordx16 %0, %1, 0x110" : "=s"(A2) : "s"(P));
            asm volatile("s_load_dwordx8 %0, %1, 0x150" : "=s"(A3) : "s"(P));
            asm volatile("s_load_dwordx4 %0, %1, 0x170" : "=s"(A4) : "s"(P));
            asm volatile("s_waitcnt lgkmcnt(0)" ::: "memory");
            __builtin_amdgcn_sched_barrier(0);

            float ox = 0.f, oy = 0.f, oz = 0.f;
#pragma unroll
            for (int jj = 0; jj < 5; jj++) {
                const int o = jj * 12;
                float wj = wgt[jj];
                float rx = fmaf(AFV(o + 0), x,
                           fmaf(AFV(o + 1), y, fmaf(AFV(o + 2), z, AFV(o + 3))));
                float ry = fmaf(AFV(o + 4), x,
                           fmaf(AFV(o + 5), y, fmaf(AFV(o + 6), z, AFV(o + 7))));
                float rz = fmaf(AFV(o + 8), x,
                           fmaf(AFV(o + 9), y, fmaf(AFV(o + 10), z, AFV(o + 11))));
                ox = fmaf(wj, rx, ox);
                oy = fmaf(wj, ry, oy);
                oz = fmaf(wj, rz, oz);
            }
            if (valid) {
                out[base + 0] = ox;
                out[base + 1] = oy;
                out[base + 2] = oz;
            }
        }
    }
}

extern "C" void kernel_launch(void* const* d_in, const int* in_sizes, int n_in,
                              void* d_out, int out_size, void* d_ws, size_t ws_size,
                              hipStream_t stream) {
    const float* vsh   = (const float*)d_in[0];
    const float* g6    = (const float*)d_in[1];
    const float* neck  = (const float*)d_in[2];
    const float* jaw   = (const float*)d_in[3];
    const float* eye   = (const float*)d_in[4];
    const float* jrest = (const float*)d_in[5];
    const float* lbs   = (const float*)d_in[6];
    const float* pdirs = (const float*)d_in[7];
    float* out = (float*)d_out;
    float* params = (float*)d_ws;  // Bn * 96 floats = 384 KB

    hipLaunchKernelGGL(flame_params_kernel, dim3((Bn + 255) / 256), dim3(256), 0,
                       stream, g6, neck, jaw, eye, jrest, params);

    dim3 grid((Vn + 127) / 128, Bn / NB);
    hipLaunchKernelGGL(flame_main_kernel, grid, dim3(256), 0, stream, vsh, lbs,
                       pdirs, params, out);
}

// Round 11
// 82.169 us; speedup vs baseline: 1.2199x; 1.2199x over previous
//
#include <hip/hip_runtime.h>
#include <math.h>

constexpr int Bn = 1024, Vn = 5023;
constexpr int NB = 16;            // batches per block (2 halves x 8)
constexpr int PARAM_STRIDE = 96;  // 36 pose_feat + 5*12 A per batch (floats)

// ---------------------------------------------------------------------------
// Kernel A: per-batch pose math. 1 thread per batch.
// params layout per batch: [0..35] pose_feat (joint-1..4, row-major 3x3 - I),
//                          [36..95] A_j as 3x4 row-major, j=0..4
// ---------------------------------------------------------------------------

__device__ inline void rodrigues3(float rx, float ry, float rz, float R[9]) {
    const float eps = 1e-8f;
    float ax = rx + eps, ay = ry + eps, az = rz + eps;
    float ang = sqrtf(ax * ax + ay * ay + az * az);
    float inv = 1.0f / ang;
    float dx = rx * inv, dy = ry * inv, dz = rz * inv;
    float s = sinf(ang), c = cosf(ang), omc = 1.0f - c;
    float K[9] = {0.f, -dz, dy, dz, 0.f, -dx, -dy, dx, 0.f};
    float K2[9];
#pragma unroll
    for (int r = 0; r < 3; r++)
#pragma unroll
        for (int k = 0; k < 3; k++) {
            float acc = 0.f;
#pragma unroll
            for (int i = 0; i < 3; i++) acc += K[r * 3 + i] * K[i * 3 + k];
            K2[r * 3 + k] = acc;
        }
#pragma unroll
    for (int i = 0; i < 9; i++) R[i] = s * K[i] + omc * K2[i];
    R[0] += 1.f; R[4] += 1.f; R[8] += 1.f;
}

__device__ inline void rot6d(const float* x, float R[9]) {
    float a1x = x[0], a1y = x[1], a1z = x[2];
    float a2x = x[3], a2y = x[4], a2z = x[5];
    float n1 = sqrtf(a1x * a1x + a1y * a1y + a1z * a1z);
    float b1x = a1x / n1, b1y = a1y / n1, b1z = a1z / n1;
    float d = b1x * a2x + b1y * a2y + b1z * a2z;
    float tx = a2x - d * b1x, ty = a2y - d * b1y, tz = a2z - d * b1z;
    float n2 = sqrtf(tx * tx + ty * ty + tz * tz);
    float b2x = tx / n2, b2y = ty / n2, b2z = tz / n2;
    float b3x = b1y * b2z - b1z * b2y;
    float b3y = b1z * b2x - b1x * b2z;
    float b3z = b1x * b2y - b1y * b2x;
    R[0] = b1x; R[1] = b1y; R[2] = b1z;
    R[3] = b2x; R[4] = b2y; R[5] = b2z;
    R[6] = b3x; R[7] = b3y; R[8] = b3z;
}

__device__ inline void compose(const float* Rp, const float* tp,
                               const float* Ri, const float* ti,
                               float* Ro, float* to) {
#pragma unroll
    for (int r = 0; r < 3; r++) {
#pragma unroll
        for (int c = 0; c < 3; c++) {
            Ro[r * 3 + c] = Rp[r * 3 + 0] * Ri[0 * 3 + c] +
                            Rp[r * 3 + 1] * Ri[1 * 3 + c] +
                            Rp[r * 3 + 2] * Ri[2 * 3 + c];
        }
        to[r] = Rp[r * 3 + 0] * ti[0] + Rp[r * 3 + 1] * ti[1] +
                Rp[r * 3 + 2] * ti[2] + tp[r];
    }
}

__global__ void flame_params_kernel(const float* __restrict__ g6,
                                    const float* __restrict__ neck,
                                    const float* __restrict__ jaw,
                                    const float* __restrict__ eye,
                                    const float* __restrict__ jrest,
                                    float* __restrict__ params) {
    int b = blockIdx.x * blockDim.x + threadIdx.x;
    if (b >= Bn) return;

    float R[5][9];
    rot6d(g6 + b * 6, R[0]);
    rodrigues3(neck[b * 3 + 0], neck[b * 3 + 1], neck[b * 3 + 2], R[1]);
    rodrigues3(jaw[b * 3 + 0], jaw[b * 3 + 1], jaw[b * 3 + 2], R[2]);
    rodrigues3(eye[b * 6 + 0], eye[b * 6 + 1], eye[b * 6 + 2], R[3]);
    rodrigues3(eye[b * 6 + 3], eye[b * 6 + 4], eye[b * 6 + 5], R[4]);

    float j[5][3];
#pragma unroll
    for (int i = 0; i < 5; i++) {
        j[i][0] = jrest[b * 15 + i * 3 + 0];
        j[i][1] = jrest[b * 15 + i * 3 + 1];
        j[i][2] = jrest[b * 15 + i * 3 + 2];
    }
    float rel[5][3];
#pragma unroll
    for (int c = 0; c < 3; c++) {
        rel[0][c] = j[0][c];
        rel[1][c] = j[1][c] - j[0][c];
        rel[2][c] = j[2][c] - j[1][c];
        rel[3][c] = j[3][c] - j[1][c];
        rel[4][c] = j[4][c] - j[1][c];
    }

    float CR[5][9], CT[5][3];
#pragma unroll
    for (int i = 0; i < 9; i++) CR[0][i] = R[0][i];
#pragma unroll
    for (int c = 0; c < 3; c++) CT[0][c] = rel[0][c];
    compose(CR[0], CT[0], R[1], rel[1], CR[1], CT[1]);
    compose(CR[1], CT[1], R[2], rel[2], CR[2], CT[2]);
    compose(CR[1], CT[1], R[3], rel[3], CR[3], CT[3]);
    compose(CR[1], CT[1], R[4], rel[4], CR[4], CT[4]);

    float* P = params + b * PARAM_STRIDE;
#pragma unroll
    for (int jj = 0; jj < 4; jj++)
#pragma unroll
        for (int r = 0; r < 3; r++)
#pragma unroll
            for (int c = 0; c < 3; c++)
                P[jj * 9 + r * 3 + c] = R[jj + 1][r * 3 + c] - (r == c ? 1.f : 0.f);
#pragma unroll
    for (int i = 0; i < 5; i++) {
#pragma unroll
        for (int r = 0; r < 3; r++) {
            float t = CT[i][r] - (CR[i][r * 3 + 0] * j[i][0] +
                                  CR[i][r * 3 + 1] * j[i][1] +
                                  CR[i][r * 3 + 2] * j[i][2]);
            P[36 + i * 12 + r * 4 + 0] = CR[i][r * 3 + 0];
            P[36 + i * 12 + r * 4 + 1] = CR[i][r * 3 + 1];
            P[36 + i * 12 + r * 4 + 2] = CR[i][r * 3 + 2];
            P[36 + i * 12 + r * 4 + 3] = t;
        }
    }
}

// ---------------------------------------------------------------------------
// Kernel B. 10-round audit: (a) pd via vL1D = 8.7 MB/CU at 64 B/cyc = ~56us,
// the R1 floor; (b) ANY register window >~30 floats spills (R5/R6/R10);
// (c) LDS residency works but needs occupancy (R7's 2 blocks/CU failed).
// Design: pd packed bf16 in LDS (halved bytes, 2x pipe BW), consumed as
// uint2 per ds_read_b64 immediately for a PAIR of batches (no window).
// 128-vertex tile = 27.6 KB LDS -> 4-5 blocks/CU; 256 thr = 128 vt x 2
// batch-halves; params as plain float4 broadcasts (R4-proven).
// ---------------------------------------------------------------------------

__device__ inline uint32_t pack_bf2(float a, float b) {
    uint32_t ua = __float_as_uint(a);
    uint32_t ub = __float_as_uint(b);
    uint32_t ra = (ua + 0x7FFFu + ((ua >> 16) & 1u)) >> 16;
    uint32_t rb = (ub + 0x7FFFu + ((ub >> 16) & 1u)) >> 16;
    return (ra & 0xFFFFu) | (rb << 16);
}
__device__ inline float blo(uint32_t d) { return __uint_as_float(d << 16); }
__device__ inline float bhi(uint32_t d) { return __uint_as_float(d); }  // raw: ok

__global__ __launch_bounds__(256, 4) void flame_main_kernel(
    const float* __restrict__ vsh, const float* __restrict__ lbs,
    const float* __restrict__ pdirs, const float* __restrict__ params,
    float* __restrict__ out) {
    const int tid = threadIdx.x;
    const int vt = tid & 127;
    const int bh = tid >> 7;
    const int v = blockIdx.x * 128 + vt;
    const bool valid = v < Vn;
    const int vc = valid ? v : (Vn - 1);
    const int bstart = blockIdx.y * NB + bh * (NB / 2);

    __shared__ uint32_t shd[128 * 54];  // 27,648 B

    // ---- stage 128 pd rows f32 -> packed bf16(RNE), coalesced float2 ----
    {
        const size_t g0 = (size_t)blockIdx.x * 128 * 108;
        const size_t gmax = (size_t)Vn * 108 - 2;
#pragma unroll
        for (int i = 0; i < 27; i++) {
            int p = i * 256 + tid;  // packed-dword index [0, 6912)
            size_t g = g0 + (size_t)p * 2;
            if (g > gmax) g = gmax;
            float2 f = *reinterpret_cast<const float2*>(pdirs + g);
            shd[p] = pack_bf2(f.x, f.y);
        }
    }
    __syncthreads();

    float wgt[5];
#pragma unroll
    for (int jj = 0; jj < 5; jj++) wgt[jj] = lbs[(size_t)vc * 5 + jj];

    const uint2* __restrict__ my =
        reinterpret_cast<const uint2*>(shd + vt * 54);  // 27 uint2, 8B-aligned

#pragma unroll 1
    for (int pr = 0; pr < NB / 4; pr++) {
        const int bA = bstart + pr * 2;
        const int bB = bA + 1;
        const float4* __restrict__ PA =
            reinterpret_cast<const float4*>(params + (size_t)bA * PARAM_STRIDE);
        const float4* __restrict__ PB =
            reinterpret_cast<const float4*>(params + (size_t)bB * PARAM_STRIDE);
        const size_t baseA = ((size_t)bA * Vn + vc) * 3;
        const size_t baseB = ((size_t)bB * Vn + vc) * 3;

        float axA = vsh[baseA + 0], ayA = vsh[baseA + 1], azA = vsh[baseA + 2];
        float axB = vsh[baseB + 0], ayB = vsh[baseB + 1], azB = vsh[baseB + 2];

#pragma unroll
        for (int g = 0; g < 9; g++) {
            float4 fA = PA[g];
            float4 fB = PB[g];
            uint2 c0 = my[3 * g + 0];
            uint2 c1 = my[3 * g + 1];
            uint2 c2 = my[3 * g + 2];
            float p0 = blo(c0.x), p1 = bhi(c0.x), p2 = blo(c0.y);
            float p3 = bhi(c0.y), p4 = blo(c1.x), p5 = bhi(c1.x);
            float p6 = blo(c1.y), p7 = bhi(c1.y), p8 = blo(c2.x);
            float p9 = bhi(c2.x), p10 = blo(c2.y), p11 = bhi(c2.y);

            axA = fmaf(fA.x, p0, axA); ayA = fmaf(fA.x, p1, ayA); azA = fmaf(fA.x, p2, azA);
            axB = fmaf(fB.x, p0, axB); ayB = fmaf(fB.x, p1, ayB); azB = fmaf(fB.x, p2, azB);
            axA = fmaf(fA.y, p3, axA); ayA = fmaf(fA.y, p4, ayA); azA = fmaf(fA.y, p5, azA);
            axB = fmaf(fB.y, p3, axB); ayB = fmaf(fB.y, p4, ayB); azB = fmaf(fB.y, p5, azB);
            axA = fmaf(fA.z, p6, axA); ayA = fmaf(fA.z, p7, ayA); azA = fmaf(fA.z, p8, azA);
            axB = fmaf(fB.z, p6, axB); ayB = fmaf(fB.z, p7, ayB); azB = fmaf(fB.z, p8, azB);
            axA = fmaf(fA.w, p9, axA); ayA = fmaf(fA.w, p10, ayA); azA = fmaf(fA.w, p11, azA);
            axB = fmaf(fB.w, p9, axB); ayB = fmaf(fB.w, p10, ayB); azB = fmaf(fB.w, p11, azB);
        }

        // ---- LBS both batches: 15 float4 broadcasts each ----
        float oxA = 0.f, oyA = 0.f, ozA = 0.f;
        float oxB = 0.f, oyB = 0.f, ozB = 0.f;
#pragma unroll
        for (int jj = 0; jj < 5; jj++) {
            float wj = wgt[jj];
            float4 r0 = PA[9 + jj * 3 + 0];
            float4 r1 = PA[9 + jj * 3 + 1];
            float4 r2 = PA[9 + jj * 3 + 2];
            float rx = fmaf(r0.x, axA, fmaf(r0.y, ayA, fmaf(r0.z, azA, r0.w)));
            float ry = fmaf(r1.x, axA, fmaf(r1.y, ayA, fmaf(r1.z, azA, r1.w)));
            float rz = fmaf(r2.x, axA, fmaf(r2.y, ayA, fmaf(r2.z, azA, r2.w)));
            oxA = fmaf(wj, rx, oxA);
            oyA = fmaf(wj, ry, oyA);
            ozA = fmaf(wj, rz, ozA);
            float4 s0 = PB[9 + jj * 3 + 0];
            float4 s1 = PB[9 + jj * 3 + 1];
            float4 s2 = PB[9 + jj * 3 + 2];
            float sx = fmaf(s0.x, axB, fmaf(s0.y, ayB, fmaf(s0.z, azB, s0.w)));
            float sy = fmaf(s1.x, axB, fmaf(s1.y, ayB, fmaf(s1.z, azB, s1.w)));
            float sz = fmaf(s2.x, axB, fmaf(s2.y, ayB, fmaf(s2.z, azB, s2.w)));
            oxB = fmaf(wj, sx, oxB);
            oyB = fmaf(wj, sy, oyB);
            ozB = fmaf(wj, sz, ozB);
        }
        if (valid) {
            out[baseA + 0] = oxA;
            out[baseA + 1] = oyA;
            out[baseA + 2] = ozA;
            out[baseB + 0] = oxB;
            out[baseB + 1] = oyB;
            out[baseB + 2] = ozB;
        }
    }
}

extern "C" void kernel_launch(void* const* d_in, const int* in_sizes, int n_in,
                              void* d_out, int out_size, void* d_ws, size_t ws_size,
                              hipStream_t stream) {
    const float* vsh   = (const float*)d_in[0];
    const float* g6    = (const float*)d_in[1];
    const float* neck  = (const float*)d_in[2];
    const float* jaw   = (const float*)d_in[3];
    const float* eye   = (const float*)d_in[4];
    const float* jrest = (const float*)d_in[5];
    const float* lbs   = (const float*)d_in[6];
    const float* pdirs = (const float*)d_in[7];
    float* out = (float*)d_out;
    float* params = (float*)d_ws;  // Bn * 96 floats = 384 KB

    hipLaunchKernelGGL(flame_params_kernel, dim3((Bn + 255) / 256), dim3(256), 0,
                       stream, g6, neck, jaw, eye, jrest, params);

    dim3 grid((Vn + 127) / 128, Bn / NB);
    hipLaunchKernelGGL(flame_main_kernel, grid, dim3(256), 0, stream, vsh, lbs,
                       pdirs, params, out);
}

// Round 13
// 69.278 us; speedup vs baseline: 1.4470x; 1.1861x over previous
//
#include <hip/hip_runtime.h>
#include <math.h>

constexpr int Bn = 1024, Vn = 5023;
constexpr int NB = 16;            // batches per block (2 wave-halves x 8)
constexpr int PARAM_STRIDE = 96;  // 36 pose_feat + 5*12 A per batch (floats)

typedef int i32x16 __attribute__((ext_vector_type(16)));
typedef int i32x8 __attribute__((ext_vector_type(8)));
typedef int i32x4 __attribute__((ext_vector_type(4)));

// ---------------------------------------------------------------------------
// Kernel A: per-batch pose math. 1 thread per batch.
// params layout per batch: [0..35] pose_feat (joint-1..4, row-major 3x3 - I),
//                          [36..95] A_j as 3x4 row-major, j=0..4
// ---------------------------------------------------------------------------

__device__ inline void rodrigues3(float rx, float ry, float rz, float R[9]) {
    const float eps = 1e-8f;
    float ax = rx + eps, ay = ry + eps, az = rz + eps;
    float ang = sqrtf(ax * ax + ay * ay + az * az);
    float inv = 1.0f / ang;
    float dx = rx * inv, dy = ry * inv, dz = rz * inv;
    float s = sinf(ang), c = cosf(ang), omc = 1.0f - c;
    float K[9] = {0.f, -dz, dy, dz, 0.f, -dx, -dy, dx, 0.f};
    float K2[9];
#pragma unroll
    for (int r = 0; r < 3; r++)
#pragma unroll
        for (int k = 0; k < 3; k++) {
            float acc = 0.f;
#pragma unroll
            for (int i = 0; i < 3; i++) acc += K[r * 3 + i] * K[i * 3 + k];
            K2[r * 3 + k] = acc;
        }
#pragma unroll
    for (int i = 0; i < 9; i++) R[i] = s * K[i] + omc * K2[i];
    R[0] += 1.f; R[4] += 1.f; R[8] += 1.f;
}

__device__ inline void rot6d(const float* x, float R[9]) {
    float a1x = x[0], a1y = x[1], a1z = x[2];
    float a2x = x[3], a2y = x[4], a2z = x[5];
    float n1 = sqrtf(a1x * a1x + a1y * a1y + a1z * a1z);
    float b1x = a1x / n1, b1y = a1y / n1, b1z = a1z / n1;
    float d = b1x * a2x + b1y * a2y + b1z * a2z;
    float tx = a2x - d * b1x, ty = a2y - d * b1y, tz = a2z - d * b1z;
    float n2 = sqrtf(tx * tx + ty * ty + tz * tz);
    float b2x = tx / n2, b2y = ty / n2, b2z = tz / n2;
    float b3x = b1y * b2z - b1z * b2y;
    float b3y = b1z * b2x - b1x * b2z;
    float b3z = b1x * b2y - b1y * b2x;
    R[0] = b1x; R[1] = b1y; R[2] = b1z;
    R[3] = b2x; R[4] = b2y; R[5] = b2z;
    R[6] = b3x; R[7] = b3y; R[8] = b3z;
}

__device__ inline void compose(const float* Rp, const float* tp,
                               const float* Ri, const float* ti,
                               float* Ro, float* to) {
#pragma unroll
    for (int r = 0; r < 3; r++) {
#pragma unroll
        for (int c = 0; c < 3; c++) {
            Ro[r * 3 + c] = Rp[r * 3 + 0] * Ri[0 * 3 + c] +
                            Rp[r * 3 + 1] * Ri[1 * 3 + c] +
                            Rp[r * 3 + 2] * Ri[2 * 3 + c];
        }
        to[r] = Rp[r * 3 + 0] * ti[0] + Rp[r * 3 + 1] * ti[1] +
                Rp[r * 3 + 2] * ti[2] + tp[r];
    }
}

__global__ void flame_params_kernel(const float* __restrict__ g6,
                                    const float* __restrict__ neck,
                                    const float* __restrict__ jaw,
                                    const float* __restrict__ eye,
                                    const float* __restrict__ jrest,
                                    float* __restrict__ params) {
    int b = blockIdx.x * blockDim.x + threadIdx.x;
    if (b >= Bn) return;

    float R[5][9];
    rot6d(g6 + b * 6, R[0]);
    rodrigues3(neck[b * 3 + 0], neck[b * 3 + 1], neck[b * 3 + 2], R[1]);
    rodrigues3(jaw[b * 3 + 0], jaw[b * 3 + 1], jaw[b * 3 + 2], R[2]);
    rodrigues3(eye[b * 6 + 0], eye[b * 6 + 1], eye[b * 6 + 2], R[3]);
    rodrigues3(eye[b * 6 + 3], eye[b * 6 + 4], eye[b * 6 + 5], R[4]);

    float j[5][3];
#pragma unroll
    for (int i = 0; i < 5; i++) {
        j[i][0] = jrest[b * 15 + i * 3 + 0];
        j[i][1] = jrest[b * 15 + i * 3 + 1];
        j[i][2] = jrest[b * 15 + i * 3 + 2];
    }
    float rel[5][3];
#pragma unroll
    for (int c = 0; c < 3; c++) {
        rel[0][c] = j[0][c];
        rel[1][c] = j[1][c] - j[0][c];
        rel[2][c] = j[2][c] - j[1][c];
        rel[3][c] = j[3][c] - j[1][c];
        rel[4][c] = j[4][c] - j[1][c];
    }

    float CR[5][9], CT[5][3];
#pragma unroll
    for (int i = 0; i < 9; i++) CR[0][i] = R[0][i];
#pragma unroll
    for (int c = 0; c < 3; c++) CT[0][c] = rel[0][c];
    compose(CR[0], CT[0], R[1], rel[1], CR[1], CT[1]);
    compose(CR[1], CT[1], R[2], rel[2], CR[2], CT[2]);
    compose(CR[1], CT[1], R[3], rel[3], CR[3], CT[3]);
    compose(CR[1], CT[1], R[4], rel[4], CR[4], CT[4]);

    float* P = params + b * PARAM_STRIDE;
#pragma unroll
    for (int jj = 0; jj < 4; jj++)
#pragma unroll
        for (int r = 0; r < 3; r++)
#pragma unroll
            for (int c = 0; c < 3; c++)
                P[jj * 9 + r * 3 + c] = R[jj + 1][r * 3 + c] - (r == c ? 1.f : 0.f);
#pragma unroll
    for (int i = 0; i < 5; i++) {
#pragma unroll
        for (int r = 0; r < 3; r++) {
            float t = CT[i][r] - (CR[i][r * 3 + 0] * j[i][0] +
                                  CR[i][r * 3 + 1] * j[i][1] +
                                  CR[i][r * 3 + 2] * j[i][2]);
            P[36 + i * 12 + r * 4 + 0] = CR[i][r * 3 + 0];
            P[36 + i * 12 + r * 4 + 1] = CR[i][r * 3 + 1];
            P[36 + i * 12 + r * 4 + 2] = CR[i][r * 3 + 2];
            P[36 + i * 12 + r * 4 + 3] = t;
        }
    }
}

// ---------------------------------------------------------------------------
// Kernel B. 11-round diagnosis: the floor was the vL1D broadcast path
// (48 same-address float4/pair = ~49us/CU). Params now via inline-asm s_load
// (scalar cache) with lgkmcnt(0) fused inside the asm so consumers order by
// SGPR dataflow. bh is readfirstlane'd so the param pointers are provably
// uniform -> "s" constraints get real SGPR pairs (R12's compile failure).
// pd: bf16-packed LDS, immediate-consume uint2 (R11's no-spill skeleton).
// ---------------------------------------------------------------------------

__device__ inline uint32_t pack_bf2(float a, float b) {
    uint32_t ua = __float_as_uint(a);
    uint32_t ub = __float_as_uint(b);
    uint32_t ra = (ua + 0x7FFFu + ((ua >> 16) & 1u)) >> 16;
    uint32_t rb = (ub + 0x7FFFu + ((ub >> 16) & 1u)) >> 16;
    return (ra & 0xFFFFu) | (rb << 16);
}
__device__ inline float blo(uint32_t d) { return __uint_as_float(d << 16); }
__device__ inline float bhi(uint32_t d) { return __uint_as_float(d); }  // raw hi

#define FCA(k) __int_as_float((k) < 16 ? fa0[(k)] : (k) < 32 ? fa1[(k)-16] : fa2[(k)-32])
#define FCB(k) __int_as_float((k) < 16 ? fb0[(k)] : (k) < 32 ? fb1[(k)-16] : fb2[(k)-32])
#define AFV(k)                                                        \
    __int_as_float((k) < 16 ? A0[(k)]                                 \
                   : (k) < 32 ? A1[(k) - 16]                          \
                   : (k) < 48 ? A2[(k) - 32]                          \
                   : (k) < 56 ? A3[(k) - 48] : A4[(k) - 56])

__global__ __launch_bounds__(256, 4) void flame_main_kernel(
    const float* __restrict__ vsh, const float* __restrict__ lbs,
    const float* __restrict__ pdirs, const float* __restrict__ params,
    float* __restrict__ out) {
    const int tid = threadIdx.x;
    const int vt = tid & 127;
    // tid>>7 is identical across each 64-lane wave; readfirstlane makes the
    // uniformity PROVABLE so the s_load pointers can live in SGPRs.
    const int bh = __builtin_amdgcn_readfirstlane(tid >> 7);
    const int v = blockIdx.x * 128 + vt;
    const bool valid = v < Vn;
    const int vc = valid ? v : (Vn - 1);
    const int bstart = blockIdx.y * NB + bh * (NB / 2);

    __shared__ uint32_t shd[128 * 54];  // 27,648 B

    // ---- stage 128 pd rows f32 -> packed bf16(RNE), coalesced float2 ----
    {
        const size_t g0 = (size_t)blockIdx.x * 128 * 108;
        const size_t gmax = (size_t)Vn * 108 - 2;
#pragma unroll
        for (int i = 0; i < 27; i++) {
            int p = i * 256 + tid;  // packed-dword index [0, 6912)
            size_t g = g0 + (size_t)p * 2;
            if (g > gmax) g = gmax;
            float2 f = *reinterpret_cast<const float2*>(pdirs + g);
            shd[p] = pack_bf2(f.x, f.y);
        }
    }
    __syncthreads();

    float wgt[5];
#pragma unroll
    for (int jj = 0; jj < 5; jj++) wgt[jj] = lbs[(size_t)vc * 5 + jj];

    const uint2* __restrict__ my =
        reinterpret_cast<const uint2*>(shd + vt * 54);  // 27 uint2, 8B-aligned

#pragma unroll 1
    for (int pr = 0; pr < NB / 4; pr++) {
        const int bA = bstart + pr * 2;
        const int bB = bA + 1;
        const float* PA = params + (size_t)bA * PARAM_STRIDE;
        const float* PB = params + (size_t)bB * PARAM_STRIDE;
        const size_t baseA = ((size_t)bA * Vn + vc) * 3;
        const size_t baseB = ((size_t)bB * Vn + vc) * 3;

        // pose_feat for both batches via scalar pipe; wait fused in-asm so
        // consumers are ordered by the SGPR dataflow.
        i32x16 fa0, fa1, fb0, fb1;
        i32x4 fa2, fb2;
        asm volatile(
            "s_load_dwordx16 %0, %6, 0x0\n\t"
            "s_load_dwordx16 %1, %6, 0x40\n\t"
            "s_load_dwordx4  %2, %6, 0x80\n\t"
            "s_load_dwordx16 %3, %7, 0x0\n\t"
            "s_load_dwordx16 %4, %7, 0x40\n\t"
            "s_load_dwordx4  %5, %7, 0x80\n\t"
            "s_waitcnt lgkmcnt(0)"
            : "=s"(fa0), "=s"(fa1), "=s"(fa2), "=s"(fb0), "=s"(fb1), "=s"(fb2)
            : "s"(PA), "s"(PB));

        float axA = vsh[baseA + 0], ayA = vsh[baseA + 1], azA = vsh[baseA + 2];
        float axB = vsh[baseB + 0], ayB = vsh[baseB + 1], azB = vsh[baseB + 2];

#pragma unroll
        for (int g = 0; g < 9; g++) {
            uint2 c0 = my[3 * g + 0];
            uint2 c1 = my[3 * g + 1];
            uint2 c2 = my[3 * g + 2];
            float p0 = blo(c0.x), p1 = bhi(c0.x), p2 = blo(c0.y);
            float p3 = bhi(c0.y), p4 = blo(c1.x), p5 = bhi(c1.x);
            float p6 = blo(c1.y), p7 = bhi(c1.y), p8 = blo(c2.x);
            float p9 = bhi(c2.x), p10 = blo(c2.y), p11 = bhi(c2.y);

            axA = fmaf(FCA(4*g+0), p0, axA); ayA = fmaf(FCA(4*g+0), p1, ayA); azA = fmaf(FCA(4*g+0), p2, azA);
            axB = fmaf(FCB(4*g+0), p0, axB); ayB = fmaf(FCB(4*g+0), p1, ayB); azB = fmaf(FCB(4*g+0), p2, azB);
            axA = fmaf(FCA(4*g+1), p3, axA); ayA = fmaf(FCA(4*g+1), p4, ayA); azA = fmaf(FCA(4*g+1), p5, azA);
            axB = fmaf(FCB(4*g+1), p3, axB); ayB = fmaf(FCB(4*g+1), p4, ayB); azB = fmaf(FCB(4*g+1), p5, azB);
            axA = fmaf(FCA(4*g+2), p6, axA); ayA = fmaf(FCA(4*g+2), p7, ayA); azA = fmaf(FCA(4*g+2), p8, azA);
            axB = fmaf(FCB(4*g+2), p6, axB); ayB = fmaf(FCB(4*g+2), p7, ayB); azB = fmaf(FCB(4*g+2), p8, azB);
            axA = fmaf(FCA(4*g+3), p9, axA); ayA = fmaf(FCA(4*g+3), p10, ayA); azA = fmaf(FCA(4*g+3), p11, azA);
            axB = fmaf(FCB(4*g+3), p9, axB); ayB = fmaf(FCB(4*g+3), p10, ayB); azB = fmaf(FCB(4*g+3), p11, azB);
        }

        // ---- LBS batch A: 60 A-floats via scalar pipe ----
        {
            i32x16 A0, A1, A2;
            i32x8 A3;
            i32x4 A4;
            asm volatile(
                "s_load_dwordx16 %0, %5, 0x90\n\t"
                "s_load_dwordx16 %1, %5, 0xD0\n\t"
                "s_load_dwordx16 %2, %5, 0x110\n\t"
                "s_load_dwordx8  %3, %5, 0x150\n\t"
                "s_load_dwordx4  %4, %5, 0x170\n\t"
                "s_waitcnt lgkmcnt(0)"
                : "=s"(A0), "=s"(A1), "=s"(A2), "=s"(A3), "=s"(A4)
                : "s"(PA));
            float ox = 0.f, oy = 0.f, oz = 0.f;
#pragma unroll
            for (int jj = 0; jj < 5; jj++) {
                const int o = jj * 12;
                float wj = wgt[jj];
                float rx = fmaf(AFV(o + 0), axA,
                           fmaf(AFV(o + 1), ayA, fmaf(AFV(o + 2), azA, AFV(o + 3))));
                float ry = fmaf(AFV(o + 4), axA,
                           fmaf(AFV(o + 5), ayA, fmaf(AFV(o + 6), azA, AFV(o + 7))));
                float rz = fmaf(AFV(o + 8), axA,
                           fmaf(AFV(o + 9), ayA, fmaf(AFV(o + 10), azA, AFV(o + 11))));
                ox = fmaf(wj, rx, ox);
                oy = fmaf(wj, ry, oy);
                oz = fmaf(wj, rz, oz);
            }
            if (valid) {
                out[baseA + 0] = ox;
                out[baseA + 1] = oy;
                out[baseA + 2] = oz;
            }
        }

        // ---- LBS batch B ----
        {
            i32x16 A0, A1, A2;
            i32x8 A3;
            i32x4 A4;
            asm volatile(
                "s_load_dwordx16 %0, %5, 0x90\n\t"
                "s_load_dwordx16 %1, %5, 0xD0\n\t"
                "s_load_dwordx16 %2, %5, 0x110\n\t"
                "s_load_dwordx8  %3, %5, 0x150\n\t"
                "s_load_dwordx4  %4, %5, 0x170\n\t"
                "s_waitcnt lgkmcnt(0)"
                : "=s"(A0), "=s"(A1), "=s"(A2), "=s"(A3), "=s"(A4)
                : "s"(PB));
            float ox = 0.f, oy = 0.f, oz = 0.f;
#pragma unroll
            for (int jj = 0; jj < 5; jj++) {
                const int o = jj * 12;
                float wj = wgt[jj];
                float rx = fmaf(AFV(o + 0), axB,
                           fmaf(AFV(o + 1), ayB, fmaf(AFV(o + 2), azB, AFV(o + 3))));
                float ry = fmaf(AFV(o + 4), axB,
                           fmaf(AFV(o + 5), ayB, fmaf(AFV(o + 6), azB, AFV(o + 7))));
                float rz = fmaf(AFV(o + 8), axB,
                           fmaf(AFV(o + 9), ayB, fmaf(AFV(o + 10), azB, AFV(o + 11))));
                ox = fmaf(wj, rx, ox);
                oy = fmaf(wj, ry, oy);
                oz = fmaf(wj, rz, oz);
            }
            if (valid) {
                out[baseB + 0] = ox;
                out[baseB + 1] = oy;
                out[baseB + 2] = oz;
            }
        }
    }
}

extern "C" void kernel_launch(void* const* d_in, const int* in_sizes, int n_in,
                              void* d_out, int out_size, void* d_ws, size_t ws_size,
                              hipStream_t stream) {
    const float* vsh   = (const float*)d_in[0];
    const float* g6    = (const float*)d_in[1];
    const float* neck  = (const float*)d_in[2];
    const float* jaw   = (const float*)d_in[3];
    const float* eye   = (const float*)d_in[4];
    const float* jrest = (const float*)d_in[5];
    const float* lbs   = (const float*)d_in[6];
    const float* pdirs = (const float*)d_in[7];
    float* out = (float*)d_out;
    float* params = (float*)d_ws;  // Bn * 96 floats = 384 KB

    hipLaunchKernelGGL(flame_params_kernel, dim3((Bn + 255) / 256), dim3(256), 0,
                       stream, g6, neck, jaw, eye, jrest, params);

    dim3 grid((Vn + 127) / 128, Bn / NB);
    hipLaunchKernelGGL(flame_main_kernel, grid, dim3(256), 0, stream, vsh, lbs,
                       pdirs, params, out);
}